// Round 3
// baseline (917.831 us; speedup 1.0000x reference)
//
#include <hip/hip_runtime.h>
#include <hip/hip_bf16.h>

#define N_NODES 50000
#define N_EDGES 800000
#define F_IN 128
#define HC 256
#define HEADS 4
#define HID 64
#define N_GRAPHS 64
#define N_CLASSES 16

typedef __attribute__((ext_vector_type(8))) short bfrag;    // 8 bf16 (4 VGPRs)
typedef __attribute__((ext_vector_type(4))) float f32x4;    // MFMA accumulator

__device__ __forceinline__ float wave_sum(float v) {
    #pragma unroll
    for (int off = 32; off > 0; off >>= 1) v += __shfl_xor(v, off);
    return v;
}

__device__ __forceinline__ unsigned int pack_bf2(float a, float b) {
    unsigned int ua = __bfloat16_as_ushort(__float2bfloat16(a));
    unsigned int ub = __bfloat16_as_ushort(__float2bfloat16(b));
    return ua | (ub << 16);
}

__device__ __forceinline__ float bf_lo(unsigned int u) { return __uint_as_float(u << 16); }
__device__ __forceinline__ float bf_hi(unsigned int u) { return __uint_as_float(u & 0xffff0000u); }

// ---------------- small utility kernels ----------------

__global__ void zero_f32(float* __restrict__ p, int n) {
    int i = blockIdx.x * 256 + threadIdx.x;
    if (i < n) p[i] = 0.f;
}

__global__ void deg_init(int* __restrict__ deg, int n) {
    int i = blockIdx.x * 256 + threadIdx.x;
    if (i < n) deg[i] = 1;  // self-loop
}

__global__ void deg_count(const int* __restrict__ dst, int* __restrict__ deg, int E) {
    int e = blockIdx.x * 256 + threadIdx.x;
    if (e < E) atomicAdd(&deg[dst[e]], 1);
}

// single-block exclusive scan over n=50000 ints
__global__ __launch_bounds__(1024) void scan_kernel(const int* __restrict__ deg,
                                                    int* __restrict__ rowptr,
                                                    int* __restrict__ cursor, int n) {
    __shared__ int part[1024];
    int t = threadIdx.x;
    int chunk = (n + 1023) >> 10;
    int c0 = t * chunk, c1 = min(c0 + chunk, n);
    int s = 0;
    for (int i = c0; i < c1; ++i) s += deg[i];
    part[t] = s;
    __syncthreads();
    for (int off = 1; off < 1024; off <<= 1) {
        int u = (t >= off) ? part[t - off] : 0;
        __syncthreads();
        part[t] += u;
        __syncthreads();
    }
    int run = part[t] - s;  // exclusive prefix
    for (int i = c0; i < c1; ++i) {
        rowptr[i] = run; cursor[i] = run; run += deg[i];
    }
    if (t == 1023) rowptr[n] = part[1023];
}

__global__ void csr_fill(const int* __restrict__ src, const int* __restrict__ dst,
                         int* __restrict__ cursor, int* __restrict__ csr_src, int E, int N) {
    int e = blockIdx.x * 256 + threadIdx.x;
    if (e >= E + N) return;
    int s, d;
    if (e < E) { s = src[e]; d = dst[e]; } else { s = d = e - E; }
    int pos = atomicAdd(&cursor[d], 1);
    csr_src[pos] = s;
}

// elementwise f32 -> bf16 (weights), n multiple of 4
__global__ void convert_w(const float* __restrict__ W, __hip_bfloat16* __restrict__ Wb, int n) {
    int i4 = (blockIdx.x * 256 + threadIdx.x) * 4;
    if (i4 >= n) return;
    float4 v = *reinterpret_cast<const float4*>(W + i4);
    ushort4 o;
    o.x = __bfloat16_as_ushort(__float2bfloat16(v.x));
    o.y = __bfloat16_as_ushort(__float2bfloat16(v.y));
    o.z = __bfloat16_as_ushort(__float2bfloat16(v.z));
    o.w = __bfloat16_as_ushort(__float2bfloat16(v.w));
    *reinterpret_cast<ushort4*>(Wb + i4) = o;
}

// ---------------- FastKAN via MFMA ----------------
template <int IN, bool XBF>
__global__ __launch_bounds__(256) void fastkan_mfma(
    const void* __restrict__ xin_v, const float* __restrict__ ln_g, const float* __restrict__ ln_b,
    const __hip_bfloat16* __restrict__ Wb, const float* __restrict__ att_s, const float* __restrict__ att_d,
    __hip_bfloat16* __restrict__ hout, float* __restrict__ as_out, float* __restrict__ ad_out, int nnodes)
{
    constexpr int K  = IN * 4;   // bf16 elements per basis row
    constexpr int RB = K * 2;    // row bytes (1024 or 2048)
    constexpr int DPL = IN / 64; // input dims per lane (2 or 4)
    __shared__ __align__(16) unsigned char bas[32 * RB];

    int t = threadIdx.x, lane = t & 63, w = t >> 6;
    int lc = lane & 15, lr = lane >> 4;
    int base = blockIdx.x * 32;

    // ---- basis phase: wave w fills rows 8w..8w+7 ----
    for (int j = 0; j < 8; ++j) {
        int r = w * 8 + j;
        int node = base + r;
        unsigned char* rowp = bas + r * RB;
        int swz = (r & 7) << 4;
        if (node < nnodes) {
            float xv[DPL];
            if constexpr (XBF) {
                const unsigned short* xs = (const unsigned short*)xin_v + (size_t)node * IN + DPL * lane;
                #pragma unroll
                for (int i = 0; i < DPL; ++i)
                    xv[i] = __uint_as_float((unsigned)xs[i] << 16);
            } else {
                const float* xr = (const float*)xin_v + (size_t)node * IN + DPL * lane;
                if constexpr (DPL == 2) {
                    float2 v2 = *reinterpret_cast<const float2*>(xr);
                    xv[0] = v2.x; xv[1] = v2.y;
                } else {
                    float4 v4 = *reinterpret_cast<const float4*>(xr);
                    xv[0] = v4.x; xv[1] = v4.y; xv[2] = v4.z; xv[3] = v4.w;
                }
            }
            float s = 0.f, sq = 0.f;
            #pragma unroll
            for (int i = 0; i < DPL; ++i) { s += xv[i]; sq += xv[i] * xv[i]; }
            s = wave_sum(s); sq = wave_sum(sq);
            float mean = s * (1.f / IN);
            float var  = sq * (1.f / IN) - mean * mean;
            float rs = rsqrtf(var + 1e-5f);
            unsigned int pk[DPL * 2];
            #pragma unroll
            for (int i = 0; i < DPL; ++i) {
                int d = DPL * lane + i;
                float v = (xv[i] - mean) * rs * ln_g[d] + ln_b[d];
                float t0 = (v + 2.f) * 0.75f;
                float t1 = (v + 2.f / 3.f) * 0.75f;
                float t2 = (v - 2.f / 3.f) * 0.75f;
                float t3 = (v - 2.f) * 0.75f;
                float e0 = __expf(-t0 * t0), e1 = __expf(-t1 * t1);
                float e2 = __expf(-t2 * t2), e3 = __expf(-t3 * t3);
                pk[2 * i]     = pack_bf2(e0, e1);
                pk[2 * i + 1] = pack_bf2(e2, e3);
            }
            #pragma unroll
            for (int q = 0; q < DPL / 2; ++q) {
                uint4 u; u.x = pk[4 * q]; u.y = pk[4 * q + 1]; u.z = pk[4 * q + 2]; u.w = pk[4 * q + 3];
                *reinterpret_cast<uint4*>(rowp + ((lane * DPL * 8 + q * 16) ^ swz)) = u;
            }
        } else {
            uint4 z{};
            #pragma unroll
            for (int q = 0; q < DPL / 2; ++q)
                *reinterpret_cast<uint4*>(rowp + ((lane * DPL * 8 + q * 16) ^ swz)) = z;
        }
    }
    __syncthreads();

    // ---- MFMA phase ----
    f32x4 acc[2][4] = {};
    const unsigned char* ap = bas + lc * RB;
    int aswz = (lc & 7) << 4;
    const __hip_bfloat16* wbase = Wb + (size_t)(w * 64 + lc) * K + lr * 8;

    #pragma unroll 4
    for (int ks = 0; ks < K / 32; ++ks) {
        int boff = (ks * 64 + lr * 16);
        bfrag a0 = *reinterpret_cast<const bfrag*>(ap + (boff ^ aswz));
        bfrag a1 = *reinterpret_cast<const bfrag*>(ap + 16 * RB + (boff ^ aswz));
        #pragma unroll
        for (int nf = 0; nf < 4; ++nf) {
            bfrag b = *reinterpret_cast<const bfrag*>(wbase + (size_t)nf * 16 * K + ks * 32);
            acc[0][nf] = __builtin_amdgcn_mfma_f32_16x16x32_bf16(a0, b, acc[0][nf], 0, 0, 0);
            acc[1][nf] = __builtin_amdgcn_mfma_f32_16x16x32_bf16(a1, b, acc[1][nf], 0, 0, 0);
        }
    }

    // ---- epilogue ----
    float asw[4], adw[4];
    #pragma unroll
    for (int nf = 0; nf < 4; ++nf) {
        asw[nf] = att_s[w * 64 + nf * 16 + lc];
        adw[nf] = att_d[w * 64 + nf * 16 + lc];
    }
    #pragma unroll
    for (int mf = 0; mf < 2; ++mf) {
        #pragma unroll
        for (int reg = 0; reg < 4; ++reg) {
            int node = base + mf * 16 + lr * 4 + reg;
            bool ok = node < nnodes;
            float ps = 0.f, pd = 0.f;
            #pragma unroll
            for (int nf = 0; nf < 4; ++nf) {
                float v = acc[mf][nf][reg];
                ps = fmaf(v, asw[nf], ps);
                pd = fmaf(v, adw[nf], pd);
                if (ok) hout[(size_t)node * 256 + w * 64 + nf * 16 + lc] = __float2bfloat16(v);
            }
            #pragma unroll
            for (int off = 8; off; off >>= 1) {
                ps += __shfl_xor(ps, off);
                pd += __shfl_xor(pd, off);
            }
            if (ok && lc == 0) {
                as_out[node * 4 + w] = ps;
                ad_out[node * 4 + w] = pd;
            }
        }
    }
}

// ---------------- fused GAT aggregation ----------------
template <int MODE>
__global__ __launch_bounds__(256) void gat_agg(
    const int* __restrict__ rowptr, const int* __restrict__ csr_src,
    const float* __restrict__ as_, const float* __restrict__ ad_,
    const __hip_bfloat16* __restrict__ h, const float* __restrict__ bias,
    __hip_bfloat16* __restrict__ out, const int* __restrict__ batch, float* __restrict__ pooled)
{
    int t = threadIdx.x, w = t >> 6, lane = t & 63;
    int d = blockIdx.x * 4 + w;
    int head = lane >> 4;
    int r0 = rowptr[d], r1 = rowptr[d + 1];
    float adv = ad_[d * 4 + head];
    const unsigned char* hb = (const unsigned char*)h;
    size_t loff = (size_t)lane * 8;

    float a0 = 0.f, a1 = 0.f, a2 = 0.f, a3 = 0.f, se = 0.f;
    int r = r0;
    for (; r + 4 <= r1; r += 4) {
        int s0 = csr_src[r], s1 = csr_src[r + 1], s2 = csr_src[r + 2], s3 = csr_src[r + 3];
        float b0 = as_[s0 * 4 + head], b1 = as_[s1 * 4 + head];
        float b2 = as_[s2 * 4 + head], b3 = as_[s3 * 4 + head];
        uint2 h0 = *reinterpret_cast<const uint2*>(hb + (size_t)s0 * 512 + loff);
        uint2 h1 = *reinterpret_cast<const uint2*>(hb + (size_t)s1 * 512 + loff);
        uint2 h2 = *reinterpret_cast<const uint2*>(hb + (size_t)s2 * 512 + loff);
        uint2 h3 = *reinterpret_cast<const uint2*>(hb + (size_t)s3 * 512 + loff);
        float e0 = b0 + adv; e0 = e0 > 0.f ? e0 : 0.2f * e0; e0 = __expf(e0);
        float e1 = b1 + adv; e1 = e1 > 0.f ? e1 : 0.2f * e1; e1 = __expf(e1);
        float e2 = b2 + adv; e2 = e2 > 0.f ? e2 : 0.2f * e2; e2 = __expf(e2);
        float e3 = b3 + adv; e3 = e3 > 0.f ? e3 : 0.2f * e3; e3 = __expf(e3);
        a0 = fmaf(e0, bf_lo(h0.x), a0); a1 = fmaf(e0, bf_hi(h0.x), a1);
        a2 = fmaf(e0, bf_lo(h0.y), a2); a3 = fmaf(e0, bf_hi(h0.y), a3);
        a0 = fmaf(e1, bf_lo(h1.x), a0); a1 = fmaf(e1, bf_hi(h1.x), a1);
        a2 = fmaf(e1, bf_lo(h1.y), a2); a3 = fmaf(e1, bf_hi(h1.y), a3);
        a0 = fmaf(e2, bf_lo(h2.x), a0); a1 = fmaf(e2, bf_hi(h2.x), a1);
        a2 = fmaf(e2, bf_lo(h2.y), a2); a3 = fmaf(e2, bf_hi(h2.y), a3);
        a0 = fmaf(e3, bf_lo(h3.x), a0); a1 = fmaf(e3, bf_hi(h3.x), a1);
        a2 = fmaf(e3, bf_lo(h3.y), a2); a3 = fmaf(e3, bf_hi(h3.y), a3);
        se += (e0 + e1) + (e2 + e3);
    }
    for (; r < r1; ++r) {
        int s = csr_src[r];
        float b0 = as_[s * 4 + head];
        uint2 h0 = *reinterpret_cast<const uint2*>(hb + (size_t)s * 512 + loff);
        float e0 = b0 + adv; e0 = e0 > 0.f ? e0 : 0.2f * e0; e0 = __expf(e0);
        a0 = fmaf(e0, bf_lo(h0.x), a0); a1 = fmaf(e0, bf_hi(h0.x), a1);
        a2 = fmaf(e0, bf_lo(h0.y), a2); a3 = fmaf(e0, bf_hi(h0.y), a3);
        se += e0;
    }

    float inv = 1.f / se;
    float4 bv = *reinterpret_cast<const float4*>(bias + lane * 4);
    float v0 = a0 * inv + bv.x, v1 = a1 * inv + bv.y;
    float v2 = a2 * inv + bv.z, v3 = a3 * inv + bv.w;
    v0 = v0 / (1.f + __expf(-v0));
    v1 = v1 / (1.f + __expf(-v1));
    v2 = v2 / (1.f + __expf(-v2));
    v3 = v3 / (1.f + __expf(-v3));
    if (MODE == 0) {
        ushort4 o;
        o.x = __bfloat16_as_ushort(__float2bfloat16(v0));
        o.y = __bfloat16_as_ushort(__float2bfloat16(v1));
        o.z = __bfloat16_as_ushort(__float2bfloat16(v2));
        o.w = __bfloat16_as_ushort(__float2bfloat16(v3));
        *reinterpret_cast<ushort4*>(out + (size_t)d * 256 + lane * 4) = o;
    } else {
        float* pp = pooled + (size_t)batch[d] * 256 + lane * 4;
        atomicAdd(pp + 0, v0); atomicAdd(pp + 1, v1);
        atomicAdd(pp + 2, v2); atomicAdd(pp + 3, v3);
    }
}

// readout: LN -> RBF -> [16] logits -> log_softmax, one block per graph
__global__ __launch_bounds__(256) void readout_kernel(
    const float* __restrict__ pooled, const float* __restrict__ ln_g, const float* __restrict__ ln_b,
    const float* __restrict__ Wr, float* __restrict__ out)
{
    __shared__ __align__(16) float bas[1024];
    __shared__ float red[8];
    __shared__ float part[16][17];
    int t = threadIdx.x, lane = t & 63, w = t >> 6;
    int g = blockIdx.x;
    float val = pooled[g * 256 + t];
    float s = wave_sum(val), sq = wave_sum(val * val);
    if (lane == 0) { red[w] = s; red[4 + w] = sq; }
    __syncthreads();
    float stot = red[0] + red[1] + red[2] + red[3];
    float sqtot = red[4] + red[5] + red[6] + red[7];
    float mean = stot * (1.f / 256), var = sqtot * (1.f / 256) - mean * mean;
    float rs = rsqrtf(var + 1e-5f);
    float v = (val - mean) * rs * ln_g[t] + ln_b[t];
    float t0 = (v + 2.f) * 0.75f;
    float t1 = (v + 2.f / 3.f) * 0.75f;
    float t2 = (v - 2.f / 3.f) * 0.75f;
    float t3 = (v - 2.f) * 0.75f;
    float4 e4;
    e4.x = __expf(-t0 * t0); e4.y = __expf(-t1 * t1);
    e4.z = __expf(-t2 * t2); e4.w = __expf(-t3 * t3);
    reinterpret_cast<float4*>(bas)[t] = e4;
    __syncthreads();
    int o = t & 15, slice = t >> 4;
    float p = 0.f;
    const float* wrow = Wr + o * 1024 + slice * 64;
    const float* brow = bas + slice * 64;
    #pragma unroll 8
    for (int kk = 0; kk < 64; ++kk) p = fmaf(brow[kk], wrow[kk], p);
    part[o][slice] = p;
    __syncthreads();
    if (t < 16) {
        float l = 0.f;
        #pragma unroll
        for (int s2 = 0; s2 < 16; ++s2) l += part[t][s2];
        float m = l;
        #pragma unroll
        for (int off = 8; off; off >>= 1) m = fmaxf(m, __shfl_xor(m, off));
        float ex = __expf(l - m);
        float ssum = ex;
        #pragma unroll
        for (int off = 8; off; off >>= 1) ssum += __shfl_xor(ssum, off);
        out[g * 16 + t] = l - m - logf(ssum);
    }
}

// ---------------- launch ----------------

extern "C" void kernel_launch(void* const* d_in, const int* in_sizes, int n_in,
                              void* d_out, int out_size, void* d_ws, size_t ws_size,
                              hipStream_t stream) {
    const float* x      = (const float*)d_in[0];
    const int*   edge   = (const int*)d_in[1];
    const int*   batch  = (const int*)d_in[2];
    const float* ln_g0  = (const float*)d_in[3];
    const float* ln_b0  = (const float*)d_in[4];
    const float* W0     = (const float*)d_in[5];
    const float* att_s0 = (const float*)d_in[6];
    const float* att_d0 = (const float*)d_in[7];
    const float* bias0  = (const float*)d_in[8];
    const float* ln_g1  = (const float*)d_in[9];
    const float* ln_b1  = (const float*)d_in[10];
    const float* W1     = (const float*)d_in[11];
    const float* att_s1 = (const float*)d_in[12];
    const float* att_d1 = (const float*)d_in[13];
    const float* bias1  = (const float*)d_in[14];
    const float* ln_gr  = (const float*)d_in[15];
    const float* ln_br  = (const float*)d_in[16];
    const float* Wr     = (const float*)d_in[17];
    float* outp = (float*)d_out;

    const int N = N_NODES, E = N_EDGES;
    const int* src = edge;
    const int* dst = edge + E;

    unsigned char* ws = (unsigned char*)d_ws;
    size_t off = 0;
    auto alloc = [&](size_t nbytes) {
        unsigned char* p = ws + off;
        off += (nbytes + 255) & ~(size_t)255;
        return (void*)p;
    };
    __hip_bfloat16* W0b   = (__hip_bfloat16*)alloc(256 * 512 * 2);
    __hip_bfloat16* W1b   = (__hip_bfloat16*)alloc(256 * 1024 * 2);
    __hip_bfloat16* h_bf  = (__hip_bfloat16*)alloc((size_t)N * 256 * 2);
    __hip_bfloat16* xmid  = (__hip_bfloat16*)alloc((size_t)N * 256 * 2);
    float* as_    = (float*)alloc((size_t)N * 4 * 4);
    float* ad_    = (float*)alloc((size_t)N * 4 * 4);
    int*   rowptr = (int*)alloc((N + 1) * 4);
    int*   cursor = (int*)alloc(N * 4);
    int*   deg    = (int*)alloc(N * 4);
    int*   csr_src= (int*)alloc((size_t)(E + N) * 4);
    float* pooled = (float*)alloc(N_GRAPHS * 256 * 4);

    deg_init<<<(N + 255) / 256, 256, 0, stream>>>(deg, N);
    deg_count<<<(E + 255) / 256, 256, 0, stream>>>(dst, deg, E);
    convert_w<<<(256 * 512 / 4 + 255) / 256, 256, 0, stream>>>(W0, W0b, 256 * 512);
    convert_w<<<(256 * 1024 / 4 + 255) / 256, 256, 0, stream>>>(W1, W1b, 256 * 1024);
    scan_kernel<<<1, 1024, 0, stream>>>(deg, rowptr, cursor, N);
    csr_fill<<<(E + N + 255) / 256, 256, 0, stream>>>(src, dst, cursor, csr_src, E, N);

    // layer 0
    fastkan_mfma<128, false><<<(N + 31) / 32, 256, 0, stream>>>(x, ln_g0, ln_b0, W0b,
                                                                att_s0, att_d0, h_bf, as_, ad_, N);
    gat_agg<0><<<(N + 3) / 4, 256, 0, stream>>>(rowptr, csr_src, as_, ad_, h_bf, bias0,
                                                xmid, nullptr, nullptr);

    // layer 1
    fastkan_mfma<256, true><<<(N + 31) / 32, 256, 0, stream>>>(xmid, ln_g1, ln_b1, W1b,
                                                               att_s1, att_d1, h_bf, as_, ad_, N);
    zero_f32<<<(N_GRAPHS * 256 + 255) / 256, 256, 0, stream>>>(pooled, N_GRAPHS * 256);
    gat_agg<1><<<(N + 3) / 4, 256, 0, stream>>>(rowptr, csr_src, as_, ad_, h_bf, bias1,
                                                nullptr, batch, pooled);

    // readout
    readout_kernel<<<N_GRAPHS, 256, 0, stream>>>(pooled, ln_gr, ln_br, Wr, outp);
}

// Round 5
// 776.711 us; speedup vs baseline: 1.1817x; 1.1817x over previous
//
#include <hip/hip_runtime.h>
#include <hip/hip_bf16.h>

#define N_NODES 50000
#define N_EDGES 800000
#define F_IN 128
#define HC 256
#define HEADS 4
#define HID 64
#define N_GRAPHS 64
#define N_CLASSES 16

typedef __attribute__((ext_vector_type(8))) short bfrag;    // 8 bf16 (4 VGPRs)
typedef __attribute__((ext_vector_type(4))) float f32x4;    // MFMA accumulator

__device__ __forceinline__ float wave_sum(float v) {
    #pragma unroll
    for (int off = 32; off > 0; off >>= 1) v += __shfl_xor(v, off);
    return v;
}

__device__ __forceinline__ unsigned int pack_bf2(float a, float b) {
    unsigned int ua = __bfloat16_as_ushort(__float2bfloat16(a));
    unsigned int ub = __bfloat16_as_ushort(__float2bfloat16(b));
    return ua | (ub << 16);
}

__device__ __forceinline__ float bfu(unsigned int u) { return __uint_as_float(u << 16); }

// ---------------- small utility kernels ----------------

__global__ void zero_f32(float* __restrict__ p, int n) {
    int i = blockIdx.x * 256 + threadIdx.x;
    if (i < n) p[i] = 0.f;
}

__global__ void deg_init(int* __restrict__ deg, int n) {
    int i = blockIdx.x * 256 + threadIdx.x;
    if (i < n) deg[i] = 1;  // self-loop
}

__global__ void deg_count(const int* __restrict__ dst, int* __restrict__ deg, int E) {
    int e = blockIdx.x * 256 + threadIdx.x;
    if (e < E) atomicAdd(&deg[dst[e]], 1);
}

// single-block exclusive scan over n=50000 ints
__global__ __launch_bounds__(1024) void scan_kernel(const int* __restrict__ deg,
                                                    int* __restrict__ rowptr,
                                                    int* __restrict__ cursor, int n) {
    __shared__ int part[1024];
    int t = threadIdx.x;
    int chunk = (n + 1023) >> 10;
    int c0 = t * chunk, c1 = min(c0 + chunk, n);
    int s = 0;
    for (int i = c0; i < c1; ++i) s += deg[i];
    part[t] = s;
    __syncthreads();
    for (int off = 1; off < 1024; off <<= 1) {
        int u = (t >= off) ? part[t - off] : 0;
        __syncthreads();
        part[t] += u;
        __syncthreads();
    }
    int run = part[t] - s;  // exclusive prefix
    for (int i = c0; i < c1; ++i) {
        rowptr[i] = run; cursor[i] = run; run += deg[i];
    }
    if (t == 1023) rowptr[n] = part[1023];
}

__global__ void csr_fill(const int* __restrict__ src, const int* __restrict__ dst,
                         int* __restrict__ cursor, int* __restrict__ csr_src, int E, int N) {
    int e = blockIdx.x * 256 + threadIdx.x;
    if (e >= E + N) return;
    int s, d;
    if (e < E) { s = src[e]; d = dst[e]; } else { s = d = e - E; }
    int pos = atomicAdd(&cursor[d], 1);
    csr_src[pos] = s;
}

// elementwise f32 -> bf16 (weights), n multiple of 4
__global__ void convert_w(const float* __restrict__ W, __hip_bfloat16* __restrict__ Wb, int n) {
    int i4 = (blockIdx.x * 256 + threadIdx.x) * 4;
    if (i4 >= n) return;
    float4 v = *reinterpret_cast<const float4*>(W + i4);
    ushort4 o;
    o.x = __bfloat16_as_ushort(__float2bfloat16(v.x));
    o.y = __bfloat16_as_ushort(__float2bfloat16(v.y));
    o.z = __bfloat16_as_ushort(__float2bfloat16(v.z));
    o.w = __bfloat16_as_ushort(__float2bfloat16(v.w));
    *reinterpret_cast<ushort4*>(Wb + i4) = o;
}

// ---------------- FastKAN via MFMA ----------------
// 32 nodes/block, 256 threads (4 waves). Wave w owns output cols [64w,64w+64) = head w.
// Basis (LN -> RBF) staged in LDS as bf16, row-major [32][K], XOR-swizzled (byte ^= (row&7)<<4).
template <int IN, bool XBF>
__global__ __launch_bounds__(256) void fastkan_mfma(
    const void* __restrict__ xin_v, const float* __restrict__ ln_g, const float* __restrict__ ln_b,
    const __hip_bfloat16* __restrict__ Wb, const float* __restrict__ att_s, const float* __restrict__ att_d,
    __hip_bfloat16* __restrict__ hout, float* __restrict__ as_out, float* __restrict__ ad_out, int nnodes)
{
    constexpr int K  = IN * 4;   // bf16 elements per basis row
    constexpr int RB = K * 2;    // row bytes (1024 or 2048)
    constexpr int DPL = IN / 64; // input dims per lane (2 or 4)
    __shared__ __align__(16) unsigned char bas[32 * RB];

    int t = threadIdx.x, lane = t & 63, w = t >> 6;
    int lc = lane & 15, lr = lane >> 4;
    int base = blockIdx.x * 32;

    // ---- basis phase: wave w fills rows 8w..8w+7 ----
    for (int j = 0; j < 8; ++j) {
        int r = w * 8 + j;
        int node = base + r;
        unsigned char* rowp = bas + r * RB;
        int swz = (r & 7) << 4;
        if (node < nnodes) {
            float xv[DPL];
            if constexpr (XBF) {
                const unsigned short* xs = (const unsigned short*)xin_v + (size_t)node * IN + DPL * lane;
                ushort4 u = *reinterpret_cast<const ushort4*>(xs);
                xv[0] = bfu(u.x); xv[1] = bfu(u.y); xv[2] = bfu(u.z); xv[3] = bfu(u.w);
            } else {
                const float* xr = (const float*)xin_v + (size_t)node * IN + DPL * lane;
                if constexpr (DPL == 2) {
                    float2 v2 = *reinterpret_cast<const float2*>(xr);
                    xv[0] = v2.x; xv[1] = v2.y;
                } else {
                    float4 v4 = *reinterpret_cast<const float4*>(xr);
                    xv[0] = v4.x; xv[1] = v4.y; xv[2] = v4.z; xv[3] = v4.w;
                }
            }
            float s = 0.f, sq = 0.f;
            #pragma unroll
            for (int i = 0; i < DPL; ++i) { s += xv[i]; sq += xv[i] * xv[i]; }
            s = wave_sum(s); sq = wave_sum(sq);
            float mean = s * (1.f / IN);
            float var  = sq * (1.f / IN) - mean * mean;
            float rs = rsqrtf(var + 1e-5f);
            unsigned int pk[DPL * 2];
            #pragma unroll
            for (int i = 0; i < DPL; ++i) {
                int d = DPL * lane + i;
                float v = (xv[i] - mean) * rs * ln_g[d] + ln_b[d];
                float t0 = (v + 2.f) * 0.75f;
                float t1 = (v + 2.f / 3.f) * 0.75f;
                float t2 = (v - 2.f / 3.f) * 0.75f;
                float t3 = (v - 2.f) * 0.75f;
                float e0 = __expf(-t0 * t0), e1 = __expf(-t1 * t1);
                float e2 = __expf(-t2 * t2), e3 = __expf(-t3 * t3);
                pk[2 * i]     = pack_bf2(e0, e1);
                pk[2 * i + 1] = pack_bf2(e2, e3);
            }
            #pragma unroll
            for (int q = 0; q < DPL / 2; ++q) {
                uint4 u; u.x = pk[4 * q]; u.y = pk[4 * q + 1]; u.z = pk[4 * q + 2]; u.w = pk[4 * q + 3];
                *reinterpret_cast<uint4*>(rowp + ((lane * DPL * 8 + q * 16) ^ swz)) = u;
            }
        } else {
            uint4 z{};
            #pragma unroll
            for (int q = 0; q < DPL / 2; ++q)
                *reinterpret_cast<uint4*>(rowp + ((lane * DPL * 8 + q * 16) ^ swz)) = z;
        }
    }
    __syncthreads();

    // ---- MFMA phase ----
    f32x4 acc[2][4] = {};
    const unsigned char* ap = bas + lc * RB;
    int aswz = (lc & 7) << 4;
    const __hip_bfloat16* wbase = Wb + (size_t)(w * 64 + lc) * K + lr * 8;

    #pragma unroll 4
    for (int ks = 0; ks < K / 32; ++ks) {
        int boff = (ks * 64 + lr * 16);
        bfrag a0 = *reinterpret_cast<const bfrag*>(ap + (boff ^ aswz));
        bfrag a1 = *reinterpret_cast<const bfrag*>(ap + 16 * RB + (boff ^ aswz));
        #pragma unroll
        for (int nf = 0; nf < 4; ++nf) {
            bfrag b = *reinterpret_cast<const bfrag*>(wbase + (size_t)nf * 16 * K + ks * 32);
            acc[0][nf] = __builtin_amdgcn_mfma_f32_16x16x32_bf16(a0, b, acc[0][nf], 0, 0, 0);
            acc[1][nf] = __builtin_amdgcn_mfma_f32_16x16x32_bf16(a1, b, acc[1][nf], 0, 0, 0);
        }
    }

    // ---- epilogue: C/D layout col=lane&15, row=(lane>>4)*4+reg ----
    float asw[4], adw[4];
    #pragma unroll
    for (int nf = 0; nf < 4; ++nf) {
        asw[nf] = att_s[w * 64 + nf * 16 + lc];
        adw[nf] = att_d[w * 64 + nf * 16 + lc];
    }
    #pragma unroll
    for (int mf = 0; mf < 2; ++mf) {
        #pragma unroll
        for (int reg = 0; reg < 4; ++reg) {
            int node = base + mf * 16 + lr * 4 + reg;
            bool ok = node < nnodes;
            float ps = 0.f, pd = 0.f;
            #pragma unroll
            for (int nf = 0; nf < 4; ++nf) {
                float v = acc[mf][nf][reg];
                ps = fmaf(v, asw[nf], ps);
                pd = fmaf(v, adw[nf], pd);
                if (ok) hout[(size_t)node * 256 + w * 64 + nf * 16 + lc] = __float2bfloat16(v);
            }
            #pragma unroll
            for (int off = 8; off; off >>= 1) {
                ps += __shfl_xor(ps, off);
                pd += __shfl_xor(pd, off);
            }
            if (ok && lc == 0) {
                as_out[node * 4 + w] = ps;
                ad_out[node * 4 + w] = pd;
            }
        }
    }
}

// ---------------- fused GAT aggregation ----------------
// Block per dst node (256 threads = 4 waves), thread t owns column t, head = t>>6.
// Attention coef computed inline: as_[src] is a wave-broadcast load, ad_[dst] loop-invariant.
// se accumulates identically in every lane of a wave (same head) -> no reduction.
__global__ __launch_bounds__(256) void gat_agg(
    const int* __restrict__ rowptr, const int* __restrict__ csr_src,
    const float* __restrict__ as_, const float* __restrict__ ad_,
    const __hip_bfloat16* __restrict__ h, const float* __restrict__ bias,
    __hip_bfloat16* __restrict__ out)
{
    int d = blockIdx.x, t = threadIdx.x, head = t >> 6;
    int r0 = rowptr[d], r1 = rowptr[d + 1];
    float adv = ad_[d * 4 + head];
    const unsigned short* hu = (const unsigned short*)h;

    float acc = 0.f, se = 0.f;
    int r = r0;
    for (; r + 4 <= r1; r += 4) {
        int s0 = csr_src[r], s1 = csr_src[r + 1], s2 = csr_src[r + 2], s3 = csr_src[r + 3];
        float b0 = as_[s0 * 4 + head], b1 = as_[s1 * 4 + head];
        float b2 = as_[s2 * 4 + head], b3 = as_[s3 * 4 + head];
        unsigned int u0 = hu[(size_t)s0 * 256 + t];
        unsigned int u1 = hu[(size_t)s1 * 256 + t];
        unsigned int u2 = hu[(size_t)s2 * 256 + t];
        unsigned int u3 = hu[(size_t)s3 * 256 + t];
        float e0 = b0 + adv; e0 = e0 > 0.f ? e0 : 0.2f * e0; e0 = __expf(e0);
        float e1 = b1 + adv; e1 = e1 > 0.f ? e1 : 0.2f * e1; e1 = __expf(e1);
        float e2 = b2 + adv; e2 = e2 > 0.f ? e2 : 0.2f * e2; e2 = __expf(e2);
        float e3 = b3 + adv; e3 = e3 > 0.f ? e3 : 0.2f * e3; e3 = __expf(e3);
        acc = fmaf(e0, bfu(u0), acc);
        acc = fmaf(e1, bfu(u1), acc);
        acc = fmaf(e2, bfu(u2), acc);
        acc = fmaf(e3, bfu(u3), acc);
        se += (e0 + e1) + (e2 + e3);
    }
    for (; r < r1; ++r) {
        int s = csr_src[r];
        float b0 = as_[s * 4 + head];
        unsigned int u0 = hu[(size_t)s * 256 + t];
        float e0 = b0 + adv; e0 = e0 > 0.f ? e0 : 0.2f * e0; e0 = __expf(e0);
        acc = fmaf(e0, bfu(u0), acc);
        se += e0;
    }

    float val = acc / se + bias[t];
    val = val / (1.f + __expf(-val));  // silu
    out[(size_t)d * 256 + t] = __float2bfloat16(val);
}

// segment-sum pooling over sorted batch: block = (graph g, row-quarter q).
// Streaming coalesced reads; one atomicAdd per (block, col) = 65K atomics total.
__global__ __launch_bounds__(256) void pool_kernel(
    const __hip_bfloat16* __restrict__ xo, const int* __restrict__ batch,
    float* __restrict__ pooled, int N)
{
    int g = blockIdx.x >> 2, q = blockIdx.x & 3, t = threadIdx.x;
    // lower bound of g
    int lo = 0, hi = N;
    while (lo < hi) { int m = (lo + hi) >> 1; if (batch[m] < g) lo = m + 1; else hi = m; }
    int start = lo;
    hi = N;
    while (lo < hi) { int m = (lo + hi) >> 1; if (batch[m] <= g) lo = m + 1; else hi = m; }
    int end = lo;
    const unsigned short* xu = (const unsigned short*)xo;
    float acc = 0.f;
    for (int r = start + q; r < end; r += 4)
        acc += bfu(xu[(size_t)r * 256 + t]);
    atomicAdd(&pooled[g * 256 + t], acc);
}

// readout: LN -> RBF -> [16] logits -> log_softmax, one block per graph
__global__ __launch_bounds__(256) void readout_kernel(
    const float* __restrict__ pooled, const float* __restrict__ ln_g, const float* __restrict__ ln_b,
    const float* __restrict__ Wr, float* __restrict__ out)
{
    __shared__ __align__(16) float bas[1024];
    __shared__ float red[8];
    __shared__ float part[16][17];
    int t = threadIdx.x, lane = t & 63, w = t >> 6;
    int g = blockIdx.x;
    float val = pooled[g * 256 + t];
    float s = wave_sum(val), sq = wave_sum(val * val);
    if (lane == 0) { red[w] = s; red[4 + w] = sq; }
    __syncthreads();
    float stot = red[0] + red[1] + red[2] + red[3];
    float sqtot = red[4] + red[5] + red[6] + red[7];
    float mean = stot * (1.f / 256), var = sqtot * (1.f / 256) - mean * mean;
    float rs = rsqrtf(var + 1e-5f);
    float v = (val - mean) * rs * ln_g[t] + ln_b[t];
    float t0 = (v + 2.f) * 0.75f;
    float t1 = (v + 2.f / 3.f) * 0.75f;
    float t2 = (v - 2.f / 3.f) * 0.75f;
    float t3 = (v - 2.f) * 0.75f;
    float4 e4;
    e4.x = __expf(-t0 * t0); e4.y = __expf(-t1 * t1);
    e4.z = __expf(-t2 * t2); e4.w = __expf(-t3 * t3);
    reinterpret_cast<float4*>(bas)[t] = e4;
    __syncthreads();
    int o = t & 15, slice = t >> 4;
    float p = 0.f;
    const float* wrow = Wr + o * 1024 + slice * 64;
    const float* brow = bas + slice * 64;
    #pragma unroll 8
    for (int kk = 0; kk < 64; ++kk) p = fmaf(brow[kk], wrow[kk], p);
    part[o][slice] = p;
    __syncthreads();
    if (t < 16) {
        float l = 0.f;
        #pragma unroll
        for (int s2 = 0; s2 < 16; ++s2) l += part[t][s2];
        float m = l;
        #pragma unroll
        for (int off = 8; off; off >>= 1) m = fmaxf(m, __shfl_xor(m, off));
        float ex = __expf(l - m);
        float ssum = ex;
        #pragma unroll
        for (int off = 8; off; off >>= 1) ssum += __shfl_xor(ssum, off);
        out[g * 16 + t] = l - m - logf(ssum);
    }
}

// ---------------- launch ----------------

extern "C" void kernel_launch(void* const* d_in, const int* in_sizes, int n_in,
                              void* d_out, int out_size, void* d_ws, size_t ws_size,
                              hipStream_t stream) {
    const float* x      = (const float*)d_in[0];
    const int*   edge   = (const int*)d_in[1];
    const int*   batch  = (const int*)d_in[2];
    const float* ln_g0  = (const float*)d_in[3];
    const float* ln_b0  = (const float*)d_in[4];
    const float* W0     = (const float*)d_in[5];
    const float* att_s0 = (const float*)d_in[6];
    const float* att_d0 = (const float*)d_in[7];
    const float* bias0  = (const float*)d_in[8];
    const float* ln_g1  = (const float*)d_in[9];
    const float* ln_b1  = (const float*)d_in[10];
    const float* W1     = (const float*)d_in[11];
    const float* att_s1 = (const float*)d_in[12];
    const float* att_d1 = (const float*)d_in[13];
    const float* bias1  = (const float*)d_in[14];
    const float* ln_gr  = (const float*)d_in[15];
    const float* ln_br  = (const float*)d_in[16];
    const float* Wr     = (const float*)d_in[17];
    float* outp = (float*)d_out;

    const int N = N_NODES, E = N_EDGES;
    const int* src = edge;
    const int* dst = edge + E;

    unsigned char* ws = (unsigned char*)d_ws;
    size_t off = 0;
    auto alloc = [&](size_t nbytes) {
        unsigned char* p = ws + off;
        off += (nbytes + 255) & ~(size_t)255;
        return (void*)p;
    };
    __hip_bfloat16* W0b   = (__hip_bfloat16*)alloc(256 * 512 * 2);
    __hip_bfloat16* W1b   = (__hip_bfloat16*)alloc(256 * 1024 * 2);
    __hip_bfloat16* h_bf  = (__hip_bfloat16*)alloc((size_t)N * 256 * 2);
    __hip_bfloat16* xmid  = (__hip_bfloat16*)alloc((size_t)N * 256 * 2);  // also reused as layer-2 output
    float* as_    = (float*)alloc((size_t)N * 4 * 4);
    float* ad_    = (float*)alloc((size_t)N * 4 * 4);
    int*   rowptr = (int*)alloc((N + 1) * 4);
    int*   cursor = (int*)alloc(N * 4);
    int*   deg    = (int*)alloc(N * 4);
    int*   csr_src= (int*)alloc((size_t)(E + N) * 4);
    float* pooled = (float*)alloc(N_GRAPHS * 256 * 4);

    deg_init<<<(N + 255) / 256, 256, 0, stream>>>(deg, N);
    deg_count<<<(E + 255) / 256, 256, 0, stream>>>(dst, deg, E);
    convert_w<<<(256 * 512 / 4 + 255) / 256, 256, 0, stream>>>(W0, W0b, 256 * 512);
    convert_w<<<(256 * 1024 / 4 + 255) / 256, 256, 0, stream>>>(W1, W1b, 256 * 1024);
    scan_kernel<<<1, 1024, 0, stream>>>(deg, rowptr, cursor, N);
    csr_fill<<<(E + N + 255) / 256, 256, 0, stream>>>(src, dst, cursor, csr_src, E, N);

    // layer 0
    fastkan_mfma<128, false><<<(N + 31) / 32, 256, 0, stream>>>(x, ln_g0, ln_b0, W0b,
                                                                att_s0, att_d0, h_bf, as_, ad_, N);
    gat_agg<<<N, 256, 0, stream>>>(rowptr, csr_src, as_, ad_, h_bf, bias0, xmid);

    // layer 1
    fastkan_mfma<256, true><<<(N + 31) / 32, 256, 0, stream>>>(xmid, ln_g1, ln_b1, W1b,
                                                               att_s1, att_d1, h_bf, as_, ad_, N);
    gat_agg<<<N, 256, 0, stream>>>(rowptr, csr_src, as_, ad_, h_bf, bias1, xmid);

    // pooling (batch sorted -> segmented streaming sum) + readout
    zero_f32<<<(N_GRAPHS * 256 + 255) / 256, 256, 0, stream>>>(pooled, N_GRAPHS * 256);
    pool_kernel<<<N_GRAPHS * 4, 256, 0, stream>>>(xmid, batch, pooled, N);
    readout_kernel<<<N_GRAPHS, 256, 0, stream>>>(pooled, ln_gr, ln_br, Wr, outp);
}